// Round 1
// 283.907 us; speedup vs baseline: 1.0082x; 1.0082x over previous
//
#include <hip/hip_runtime.h>
#include <math.h>

#define BB 64
#define PP 1024
#define DD 768
#define SPLITS 16                         // blocks per batch
#define RPW (PP / SPLITS / 4)             // rows per wave = 16

// ---------------------------------------------------------------------------
// qw[d] = sum_e q[e] * W[e*D + d]  — grid (3, 64), atomicAdd combine
// ---------------------------------------------------------------------------
__global__ __launch_bounds__(256) void qw_kernel(const float* __restrict__ q,
                                                 const float* __restrict__ W,
                                                 float* __restrict__ qw) {
    int d  = blockIdx.x * 256 + threadIdx.x;
    int e0 = blockIdx.y * 12;
    float acc = 0.f;
#pragma unroll
    for (int i = 0; i < 12; ++i) {
        int e = e0 + i;
        acc += q[e] * W[(size_t)e * DD + d];
    }
    atomicAdd(&qw[d], acc);
}

// ---------------------------------------------------------------------------
// Register-resident fused attention pool. No LDS staging, no per-tile
// barriers. Each wave owns RPW=16 rows; a row's 768 floats live in 12
// VGPRs/lane (3 float4). Per row: 3 coalesced global loads (next row
// prefetched), 12-FMA dot vs register qw fragment, 6-step shfl_xor wave
// reduction, online-softmax update fully in registers. Waves combine via
// 12 KB LDS at the end -> one partial (M, L, acc[768]) per block.
// ---------------------------------------------------------------------------
__global__ __launch_bounds__(256) void fused_kernel(const float* __restrict__ z,
                                                    const float* __restrict__ qw,
                                                    float* __restrict__ macc,
                                                    float* __restrict__ ml) {
    const float scale = 0.03608439182435161f;   // 1/sqrt(768)
    int b     = blockIdx.x;
    int split = blockIdx.y;
    int tid   = threadIdx.x;
    int w     = tid >> 6;                 // wave 0..3
    int lane  = tid & 63;

    // qw fragment: lane owns d = {4*lane..4*lane+3} + j*256
    const float4* q4 = (const float4*)qw;
    float4 qf0 = q4[lane], qf1 = q4[lane + 64], qf2 = q4[lane + 128];

    // this wave's first row
    const float4* rp = (const float4*)(z + ((size_t)b * PP + split * (PP / SPLITS)
                                            + w * RPW) * DD);

    float m = -INFINITY, l = 0.f;
    float4 a0 = {0.f,0.f,0.f,0.f}, a1 = {0.f,0.f,0.f,0.f}, a2 = {0.f,0.f,0.f,0.f};

    float4 c0 = rp[lane], c1 = rp[lane + 64], c2 = rp[lane + 128];

#pragma unroll
    for (int r = 0; r < RPW; ++r) {
        // prefetch next row while we compute on the current one
        float4 n0 = c0, n1 = c1, n2 = c2;
        if (r + 1 < RPW) {
            const float4* np = rp + (size_t)(r + 1) * (DD / 4);
            n0 = np[lane]; n1 = np[lane + 64]; n2 = np[lane + 128];
        }

        // dot(z_row, qw): 12 FMAs then full-wave butterfly reduce
        float part = c0.x*qf0.x + c0.y*qf0.y + c0.z*qf0.z + c0.w*qf0.w
                   + c1.x*qf1.x + c1.y*qf1.y + c1.z*qf1.z + c1.w*qf1.w
                   + c2.x*qf2.x + c2.y*qf2.y + c2.z*qf2.z + c2.w*qf2.w;
#pragma unroll
        for (int mask = 32; mask >= 1; mask >>= 1)
            part += __shfl_xor(part, mask, 64);
        float s = part * scale;

        // online softmax; rescale branch is wave-uniform (s uniform after reduce)
        if (s > m) {
            float alpha = __expf(m - s);      // first row: exp(-inf)=0
            l *= alpha;
            a0.x *= alpha; a0.y *= alpha; a0.z *= alpha; a0.w *= alpha;
            a1.x *= alpha; a1.y *= alpha; a1.z *= alpha; a1.w *= alpha;
            a2.x *= alpha; a2.y *= alpha; a2.z *= alpha; a2.w *= alpha;
            m = s;
        }
        float e = __expf(s - m);
        l += e;
        a0.x += e * c0.x; a0.y += e * c0.y; a0.z += e * c0.z; a0.w += e * c0.w;
        a1.x += e * c1.x; a1.y += e * c1.y; a1.z += e * c1.z; a1.w += e * c1.w;
        a2.x += e * c2.x; a2.y += e * c2.y; a2.z += e * c2.z; a2.w += e * c2.w;

        c0 = n0; c1 = n1; c2 = n2;
    }

    // ---- combine the 4 waves' partials in LDS -> one block partial ----
    __shared__ float sacc[4][DD];             // 12 KB
    __shared__ float sml[4][2];
    float4* sa = (float4*)sacc[w];
    sa[lane] = a0; sa[lane + 64] = a1; sa[lane + 128] = a2;
    if (lane == 0) { sml[w][0] = m; sml[w][1] = l; }
    __syncthreads();

    float M = fmaxf(fmaxf(sml[0][0], sml[1][0]), fmaxf(sml[2][0], sml[3][0]));
    float wk[4], L = 0.f;
#pragma unroll
    for (int k = 0; k < 4; ++k) { wk[k] = __expf(sml[k][0] - M); L += wk[k] * sml[k][1]; }

    int pidx = b * SPLITS + split;
    float* ap = macc + (size_t)pidx * DD;
#pragma unroll
    for (int j = 0; j < 3; ++j) {
        int d = j * 256 + tid;
        float acc = 0.f;
#pragma unroll
        for (int k = 0; k < 4; ++k) acc += wk[k] * sacc[k][d];
        ap[d] = acc;
    }
    if (tid == 0) { ml[pidx * 2] = M; ml[pidx * 2 + 1] = L; }
}

// ---------------------------------------------------------------------------
// Combine 16 partials per batch. grid (64, 3): block handles 256 d's.
//   M = max M_k; L = sum exp(M_k-M) L_k; out[d] = sum exp(M_k-M) acc_k[d] / L
// ---------------------------------------------------------------------------
__global__ __launch_bounds__(256) void reduce_kernel(const float* __restrict__ macc,
                                                     const float* __restrict__ ml,
                                                     float* __restrict__ out) {
    int b   = blockIdx.x;
    int j   = blockIdx.y;
    int tid = threadIdx.x;

    float mk[SPLITS], lk[SPLITS];
#pragma unroll
    for (int k = 0; k < SPLITS; ++k) {
        mk[k] = ml[(b * SPLITS + k) * 2];
        lk[k] = ml[(b * SPLITS + k) * 2 + 1];
    }
    float M = mk[0];
#pragma unroll
    for (int k = 1; k < SPLITS; ++k) M = fmaxf(M, mk[k]);
    float L = 0.f, wk[SPLITS];
#pragma unroll
    for (int k = 0; k < SPLITS; ++k) { wk[k] = __expf(mk[k] - M); L += wk[k] * lk[k]; }
    float inv = 1.f / L;

    int d = j * 256 + tid;
    const float* base = macc + (size_t)b * SPLITS * DD;
    float acc = 0.f;
#pragma unroll
    for (int k = 0; k < SPLITS; ++k) acc += wk[k] * base[(size_t)k * DD + d];
    out[b * DD + d] = acc * inv;
}

// ---------------------------------------------------------------------------
extern "C" void kernel_launch(void* const* d_in, const int* in_sizes, int n_in,
                              void* d_out, int out_size, void* d_ws, size_t ws_size,
                              hipStream_t stream) {
    const float* z = (const float*)d_in[0];   // [B,P,D]
    const float* q = (const float*)d_in[1];   // [1,1,D]
    const float* W = (const float*)d_in[2];   // [D,D]
    float* out = (float*)d_out;               // [B,D]

    char* ws = (char*)d_ws;
    float* qw   = (float*)ws;                         // 768 floats
    float* ml   = (float*)(ws + 4096);                // 1024*2 floats
    float* macc = (float*)(ws + 4096 + 8192);         // 1024*768 floats (3.1 MB)

    hipMemsetAsync(qw, 0, DD * sizeof(float), stream);
    dim3 qg(3, 64);
    qw_kernel<<<qg, 256, 0, stream>>>(q, W, qw);
    dim3 fg(BB, SPLITS);
    fused_kernel<<<fg, 256, 0, stream>>>(z, qw, macc, ml);
    dim3 rg(BB, 3);
    reduce_kernel<<<rg, 256, 0, stream>>>(macc, ml, out);
}